// Round 1
// baseline (10205.072 us; speedup 1.0000x reference)
//
#include <hip/hip_runtime.h>

#define TPB 256

// ---------------- weight transpose: w[Cout][Cin][T] -> wT[T][Cin][Cout] ----------------
__global__ __launch_bounds__(TPB)
void wtrans_k(const float* __restrict__ w, float* __restrict__ wT,
              int Cout, int Cin, int T)
{
    __shared__ float tile[32 * (32 * 9 + 1)];
    const int rowlen = 32 * T + 1;
    const int co0 = blockIdx.y * 32;
    const int ci0 = blockIdx.x * 32;
    const int n = 32 * 32 * T;
    const int tid = threadIdx.x;
    for (int l = tid; l < n; l += TPB) {
        int co = l / (32 * T);
        int rem = l - co * (32 * T);
        int ci = rem / T;
        float v = 0.f;
        if (co0 + co < Cout && ci0 + ci < Cin)
            v = w[(size_t)(co0 + co) * Cin * T + (size_t)ci0 * T + rem];
        tile[co * rowlen + rem] = v;
    }
    __syncthreads();
    for (int l = tid; l < n; l += TPB) {
        int co = l & 31;
        int ci = (l >> 5) & 31;
        int t  = l >> 10;
        if (co0 + co < Cout && ci0 + ci < Cin)
            wT[((size_t)t * Cin + (ci0 + ci)) * Cout + (co0 + co)] = tile[co * rowlen + ci * T + t];
    }
}

// ---------------- implicit-GEMM conv ----------------
// in [B][Cin][H*W], wT [taps][Cin][Cout], out elem (b,co,p) at out + b*outBStride + co*HW + p
#define GBM 128
#define GBN 64
#define GBK 16
#define GTM 8
#define GTN 4

__global__ __launch_bounds__(TPB)
void gemm_conv_k(const float* __restrict__ in, const float* __restrict__ wT,
                 const float* __restrict__ bias, float* __restrict__ out,
                 int Cin, int Cout, int H, int W,
                 int ksize, int dil, int relu, long outBStride, int nMtiles,
                 int fusedAspp)
{
    __shared__ float Ws[GBK][GBM];
    __shared__ float Is[GBK][GBN];

    if (fusedAspp) {
        const int br = blockIdx.z;
        const long offs[4] = {0L, 524288L, 5242880L, 9961472L};
        wT  += offs[br];
        out += (long)br * (256L * 1089L);
        if (br == 0) { ksize = 1; dil = 1; }
        else         { ksize = 3; dil = (br == 1) ? 6 : (br == 2 ? 12 : 18); }
    }

    const int HW = H * W;
    const int mt = blockIdx.x % nMtiles;
    const int nt = blockIdx.x / nMtiles;
    const int b  = blockIdx.y;
    const int co0 = mt * GBM;
    const int p0  = nt * GBN;
    const int tid = threadIdx.x;

    const int wcol  = tid & 127;         // Ws stage: column (m)
    const int wrow0 = (tid >> 7) << 3;   // Ws stage: 8 k-rows per thread
    const int icol  = tid & 63;          // Is stage: column (n)
    const int irow0 = (tid >> 6) << 2;   // Is stage: 4 k-rows per thread

    const int tx = tid & 15;             // micro-tile: 16 x-groups * GTN=4 -> 64 cols
    const int ty = tid >> 4;             // 16 y-groups * GTM=8 -> 128 rows

    const int p  = p0 + icol;
    const bool pv = p < HW;
    const int py = pv ? (p / W) : 0;
    const int px = pv ? (p - py * W) : 0;
    const int y0 = p0 / W;
    const int y1 = min(p0 + GBN - 1, HW - 1) / W;

    const float* inB = in + (size_t)b * Cin * HW;
    const int taps = ksize * ksize;
    const int half = ksize >> 1;
    const bool mvalid = (co0 + wcol) < Cout;

    float acc[GTM][GTN];
#pragma unroll
    for (int i = 0; i < GTM; ++i)
#pragma unroll
        for (int j = 0; j < GTN; ++j) acc[i][j] = 0.f;

    for (int tap = 0; tap < taps; ++tap) {
        const int ky = tap / ksize;
        const int kx = tap - ky * ksize;
        const int dy = (ky - half) * dil;
        const int dx = (kx - half) * dil;
        if (y1 + dy < 0 || y0 + dy >= H) continue;   // block-uniform tap skip
        const int ny = py + dy, nx = px + dx;
        const bool nv = pv && ((unsigned)ny < (unsigned)H) && ((unsigned)nx < (unsigned)W);
        const float* ip = inB + (long)ny * W + nx;
        const float* wp = wT + (size_t)tap * Cin * Cout + co0 + wcol;
        for (int kc = 0; kc < Cin; kc += GBK) {
#pragma unroll
            for (int i = 0; i < 8; ++i) {
                const int k = wrow0 + i;
                Ws[k][wcol] = mvalid ? wp[(size_t)(kc + k) * Cout] : 0.f;
            }
#pragma unroll
            for (int i = 0; i < 4; ++i) {
                const int k = irow0 + i;
                Is[k][icol] = nv ? ip[(size_t)(kc + k) * HW] : 0.f;
            }
            __syncthreads();
#pragma unroll
            for (int k = 0; k < GBK; ++k) {
                float a[GTM], bb[GTN];
#pragma unroll
                for (int i = 0; i < GTM; ++i) a[i] = Ws[k][ty * GTM + i];
#pragma unroll
                for (int j = 0; j < GTN; ++j) bb[j] = Is[k][tx * GTN + j];
#pragma unroll
                for (int i = 0; i < GTM; ++i)
#pragma unroll
                    for (int j = 0; j < GTN; ++j)
                        acc[i][j] = fmaf(a[i], bb[j], acc[i][j]);
            }
            __syncthreads();
        }
    }

    float* outB = out + (size_t)b * outBStride;
#pragma unroll
    for (int i = 0; i < GTM; ++i) {
        const int co = co0 + ty * GTM + i;
        if (co < Cout) {
            const float bv = bias ? bias[(size_t)b * Cout + co] : 0.f;
#pragma unroll
            for (int j = 0; j < GTN; ++j) {
                const int pp = p0 + tx * GTN + j;
                if (pp < HW) {
                    float v = acc[i][j] + bv;
                    if (relu) v = fmaxf(v, 0.f);
                    outB[(size_t)co * HW + pp] = v;
                }
            }
        }
    }
}

// ---------------- global average pool (one block per (b*C+c)) ----------------
__global__ __launch_bounds__(TPB)
void gpool_k(const float* __restrict__ in, float* __restrict__ gp, int HW, float inv)
{
    const int bc = blockIdx.x;
    const float* p = in + (size_t)bc * HW;
    float s = 0.f;
    for (int i = threadIdx.x; i < HW; i += TPB) s += p[i];
#pragma unroll
    for (int off = 32; off > 0; off >>= 1) s += __shfl_down(s, off, 64);
    __shared__ float red[4];
    if ((threadIdx.x & 63) == 0) red[threadIdx.x >> 6] = s;
    __syncthreads();
    if (threadIdx.x == 0) gp[bc] = (red[0] + red[1] + red[2] + red[3]) * inv;
}

// gpr[b][c] = relu( sum_k poolT[k][c] * gp[b][k] ), k<2048, c<256
__global__ __launch_bounds__(TPB)
void poolconv_k(const float* __restrict__ poolT, const float* __restrict__ gp,
                float* __restrict__ gpr)
{
    const int b = blockIdx.x, c = threadIdx.x;
    const float* g = gp + (size_t)b * 2048;
    float s = 0.f;
    for (int k = 0; k < 2048; ++k) s = fmaf(poolT[(size_t)k * 256 + c], g[k], s);
    gpr[b * 256 + c] = fmaxf(s, 0.f);
}

// gpc[b][c] = sum_j aprojT[1024+j][c] * gpr[b][j]
__global__ __launch_bounds__(TPB)
void gpc_k(const float* __restrict__ aprojT, const float* __restrict__ gpr,
           float* __restrict__ gpc)
{
    const int b = blockIdx.x, c = threadIdx.x;
    const float* g = gpr + (size_t)b * 256;
    const float* w = aprojT + (size_t)1024 * 256;
    float s = 0.f;
    for (int j = 0; j < 256; ++j) s = fmaf(w[(size_t)j * 256 + c], g[j], s);
    gpc[b * 256 + c] = s;
}

// ---------------- bilinear upsample (jax half-pixel, clamped) into channel-offset dst ----------------
__global__ __launch_bounds__(TPB)
void upsample_k(const float* __restrict__ src, float* __restrict__ dst,
                int C, int inH, int inW, int outH, int outW,
                long dstBStride, int dstChOff, int B)
{
    const int idx = blockIdx.x * TPB + threadIdx.x;
    const int total = B * C * outH * outW;
    if (idx >= total) return;
    const int ox = idx % outW;
    int r = idx / outW;
    const int oy = r % outH; r /= outH;
    const int c = r % C;
    const int b = r / C;
    const float sx = (ox + 0.5f) * ((float)inW / (float)outW) - 0.5f;
    const float sy = (oy + 0.5f) * ((float)inH / (float)outH) - 0.5f;
    int ix0 = (int)floorf(sx), iy0 = (int)floorf(sy);
    const float fx = sx - ix0, fy = sy - iy0;
    int ix1 = min(inW - 1, max(0, ix0 + 1)); ix0 = min(inW - 1, max(0, ix0));
    int iy1 = min(inH - 1, max(0, iy0 + 1)); iy0 = min(inH - 1, max(0, iy0));
    const float* s = src + ((size_t)b * C + c) * inH * inW;
    const float v00 = s[iy0 * inW + ix0], v01 = s[iy0 * inW + ix1];
    const float v10 = s[iy1 * inW + ix0], v11 = s[iy1 * inW + ix1];
    const float v0 = v00 + (v01 - v00) * fx;
    const float v1 = v10 + (v11 - v10) * fx;
    dst[(size_t)b * dstBStride + (size_t)(dstChOff + c) * outH * outW + (size_t)oy * outW + ox]
        = v0 + (v1 - v0) * fy;
}

// ---------------- cw2 1x1 conv, small M: thread-per-pixel, NC accumulators ----------------
template <int NC>
__global__ __launch_bounds__(TPB)
void conv1x1_small(const float* __restrict__ in, const float* __restrict__ wT,
                   const float* __restrict__ bias, float* __restrict__ out, int HW)
{
    __shared__ float ws[256 * NC];
    const int tid = threadIdx.x;
    for (int l = tid; l < 256 * NC; l += TPB) ws[l] = wT[l];
    __syncthreads();
    const int b = blockIdx.y;
    const int p = blockIdx.x * TPB + tid;
    if (p >= HW) return;
    const float* inB = in + (size_t)b * 256 * HW + p;
    float acc[NC];
#pragma unroll
    for (int c = 0; c < NC; ++c) acc[c] = 0.f;
    for (int k = 0; k < 256; ++k) {
        const float x = inB[(size_t)k * HW];
#pragma unroll
        for (int c = 0; c < NC; ++c) acc[c] = fmaf(ws[k * NC + c], x, acc[c]);
    }
    float* oB = out + (size_t)b * NC * HW + p;
#pragma unroll
    for (int c = 0; c < NC; ++c) oB[(size_t)c * HW] = acc[c] + bias[c];
}

// ---------------- final: 129->513 bilinear + logits + NHWC features ----------------
template <int NC>
__global__ __launch_bounds__(TPB)
void final_k(const float* __restrict__ x, float* __restrict__ logits,
             float* __restrict__ feats)
{
    const int idx = blockIdx.x * TPB + threadIdx.x;
    const long HW = 513L * 513L;
    if (idx >= 2 * 513 * 513) return;
    const int ox = idx % 513;
    int r = idx / 513;
    const int oy = r % 513;
    const int b = r / 513;
    const float sc = 129.0f / 513.0f;
    const float sx = (ox + 0.5f) * sc - 0.5f;
    const float sy = (oy + 0.5f) * sc - 0.5f;
    int ix0 = (int)floorf(sx), iy0 = (int)floorf(sy);
    const float fx = sx - ix0, fy = sy - iy0;
    int ix1 = min(128, max(0, ix0 + 1)); ix0 = min(128, max(0, ix0));
    int iy1 = min(128, max(0, iy0 + 1)); iy0 = min(128, max(0, iy0));
    const float* xb = x + (size_t)b * NC * 16641;
    const int i00 = iy0 * 129 + ix0, i01 = iy0 * 129 + ix1;
    const int i10 = iy1 * 129 + ix0, i11 = iy1 * 129 + ix1;
    float v[NC];
    float ss = 0.f;
#pragma unroll
    for (int c = 0; c < NC; ++c) {
        const float* s = xb + (size_t)c * 16641;
        const float a0 = s[i00] + (s[i01] - s[i00]) * fx;
        const float a1 = s[i10] + (s[i11] - s[i10]) * fx;
        const float vv = a0 + (a1 - a0) * fy;
        v[c] = vv;
        ss = fmaf(vv, vv, ss);
    }
    const long pix = (long)oy * 513 + ox;
#pragma unroll
    for (int c = 0; c < NC; ++c)
        logits[((size_t)b * NC + c) * HW + pix] = fmaf(6.f, v[c], -ss - 9.f);
    float* f = feats + ((size_t)b * HW + pix) * NC;
#pragma unroll
    for (int c = 0; c < NC; ++c) f[c] = v[c];
}

__global__ void centers_k(float* __restrict__ c0, float* __restrict__ c1)
{
    const int t = blockIdx.x * 64 + threadIdx.x;
    if (t < 256) c0[t] = (t / 16 == t % 16) ? 3.f : 0.f;
    const int u = t - 256;
    if (u >= 0 && u < 289) c1[u] = (u / 17 == u % 17) ? 3.f : 0.f;
}

// ---------------- host ----------------
extern "C" void kernel_launch(void* const* d_in, const int* in_sizes, int n_in,
                              void* d_out, int out_size, void* d_ws, size_t ws_size,
                              hipStream_t stream)
{
    const float* low_level = (const float*)d_in[0];
    const float* aspp_in   = (const float*)d_in[1];
    float* ws = (float*)d_ws;
    float* o  = (float*)d_out;

    // ws arenas (floats). Total 27,935,328 floats (~107 MiB).
    float* A      = ws;               // 14,680,064: poolT/w0T..w3T; later cw1T@0, C1OUT@+1,048,576
    float* APROJT = ws + 14680064;    //    327,680
    float* PWT    = ws + 15007744;    //     12,288
    float* CW2T   = PWT + 12288;      //      4,608
    float* GP     = CW2T + 4608;      //      4,096
    float* GPR    = GP + 4096;        //        512
    float* GPC    = GPR + 512;        //        512
    float* BR     = ws + 15029760;    //  2,230,272 (branches; later aliased as XB)
    float* XB     = BR;
    float* YB     = ws + 17260032;    //    557,568
    float* CC     = ws + 17817600;    // 10,117,728
    float* C1O    = A + 1048576;      //  8,520,192 (inside A, after cw1T region)

    const long L0o = 0, L1o = 8421408, C0o = 17369154, C1oo = 17369410,
               F0o = 17369699, F1o = 25791107;

    // head-independent global pool of ASPP input
    gpool_k<<<4096, TPB, 0, stream>>>(aspp_in, GP, 1089, 1.0f / 1089.0f);

    for (int h = 0; h < 2; ++h) {
        const float* pw    = (const float*)d_in[2 + h * 10 + 0];
        const float* w0    = (const float*)d_in[2 + h * 10 + 1];
        const float* w1    = (const float*)d_in[2 + h * 10 + 2];
        const float* w2    = (const float*)d_in[2 + h * 10 + 3];
        const float* w3    = (const float*)d_in[2 + h * 10 + 4];
        const float* poolw = (const float*)d_in[2 + h * 10 + 5];
        const float* aproj = (const float*)d_in[2 + h * 10 + 6];
        const float* cw1   = (const float*)d_in[2 + h * 10 + 7];
        const float* cw2   = (const float*)d_in[2 + h * 10 + 8];
        const float* cb2   = (const float*)d_in[2 + h * 10 + 9];

        // pooled branch -> per-(b,c) bias of aproj
        wtrans_k<<<dim3(64, 8), TPB, 0, stream>>>(poolw, A, 256, 2048, 1);
        poolconv_k<<<2, TPB, 0, stream>>>(A, GP, GPR);
        wtrans_k<<<dim3(40, 8), TPB, 0, stream>>>(aproj, APROJT, 256, 1280, 1);
        gpc_k<<<2, TPB, 0, stream>>>(APROJT, GPR, GPC);

        // ASPP branch weights -> A at the offsets baked into gemm_conv_k fused mode
        wtrans_k<<<dim3(64, 8), TPB, 0, stream>>>(w0, A,           256, 2048, 1);
        wtrans_k<<<dim3(64, 8), TPB, 0, stream>>>(w1, A + 524288,  256, 2048, 9);
        wtrans_k<<<dim3(64, 8), TPB, 0, stream>>>(w2, A + 5242880, 256, 2048, 9);
        wtrans_k<<<dim3(64, 8), TPB, 0, stream>>>(w3, A + 9961472, 256, 2048, 9);
        // fused 4-branch ASPP -> BR [2][1024][1089]
        gemm_conv_k<<<dim3(2 * 18, 2, 4), TPB, 0, stream>>>(aspp_in, A, nullptr, BR,
            2048, 256, 33, 33, 1, 1, 1, 1024L * 1089L, 2, 1);
        // aproj 1x1 (+gp bias, relu) -> YB [2][256][1089]
        gemm_conv_k<<<dim3(2 * 18, 2, 1), TPB, 0, stream>>>(BR, APROJT, GPC, YB,
            1024, 256, 33, 33, 1, 1, 1, 256L * 1089L, 2, 0);
        // low-level 1x1 (48ch) -> CC channels 0..47
        wtrans_k<<<dim3(8, 2), TPB, 0, stream>>>(pw, PWT, 48, 256, 1);
        gemm_conv_k<<<dim3(261, 2, 1), TPB, 0, stream>>>(low_level, PWT, nullptr, CC,
            256, 48, 129, 129, 1, 1, 1, 304L * 16641L, 1, 0);
        // upsample 33->129 -> CC channels 48..303
        upsample_k<<<(2 * 256 * 16641 + TPB - 1) / TPB, TPB, 0, stream>>>(YB, CC,
            256, 33, 33, 129, 129, 304L * 16641L, 48, 2);
        // cw1 3x3 (304->256, relu) -> C1O
        wtrans_k<<<dim3(10, 8), TPB, 0, stream>>>(cw1, A, 256, 304, 9);
        gemm_conv_k<<<dim3(2 * 261, 2, 1), TPB, 0, stream>>>(CC, A, nullptr, C1O,
            304, 256, 129, 129, 3, 1, 1, 256L * 16641L, 2, 0);
        // cw2 1x1 + bias -> XB, then final resize/logits/features
        if (h == 0) {
            wtrans_k<<<dim3(8, 1), TPB, 0, stream>>>(cw2, CW2T, 16, 256, 1);
            conv1x1_small<16><<<dim3(66, 2), TPB, 0, stream>>>(C1O, CW2T, cb2, XB, 16641);
            final_k<16><<<2057, TPB, 0, stream>>>(XB, o + L0o, o + F0o);
        } else {
            wtrans_k<<<dim3(8, 1), TPB, 0, stream>>>(cw2, CW2T, 17, 256, 1);
            conv1x1_small<17><<<dim3(66, 2), TPB, 0, stream>>>(C1O, CW2T, cb2, XB, 16641);
            final_k<17><<<2057, TPB, 0, stream>>>(XB, o + L1o, o + F1o);
        }
    }
    centers_k<<<9, 64, 0, stream>>>(o + C0o, o + C1oo);
}

// Round 2
// 4092.578 us; speedup vs baseline: 2.4936x; 2.4936x over previous
//
#include <hip/hip_runtime.h>

#define TPB 256

typedef _Float16 f16;
typedef __attribute__((ext_vector_type(8))) _Float16 f16x8;
typedef __attribute__((ext_vector_type(16))) float f32x16;

// ---------------- weight transpose: w[Cout][Cin][T] -> wT[T][Cin][Cout] ----------------
template <typename OT>
__global__ __launch_bounds__(TPB)
void wtrans_k(const float* __restrict__ w, OT* __restrict__ wT,
              int Cout, int Cin, int T)
{
    __shared__ float tile[32 * (32 * 9 + 1)];
    const int rowlen = 32 * T + 1;
    const int co0 = blockIdx.y * 32;
    const int ci0 = blockIdx.x * 32;
    const int n = 32 * 32 * T;
    const int tid = threadIdx.x;
    for (int l = tid; l < n; l += TPB) {
        int co = l / (32 * T);
        int rem = l - co * (32 * T);
        int ci = rem / T;
        float v = 0.f;
        if (co0 + co < Cout && ci0 + ci < Cin)
            v = w[(size_t)(co0 + co) * Cin * T + (size_t)ci0 * T + rem];
        tile[co * rowlen + rem] = v;
    }
    __syncthreads();
    for (int l = tid; l < n; l += TPB) {
        int co = l & 31;
        int ci = (l >> 5) & 31;
        int t  = l >> 10;
        if (co0 + co < Cout && ci0 + ci < Cin)
            wT[((size_t)t * Cin + (ci0 + ci)) * Cout + (co0 + co)] =
                (OT)tile[co * rowlen + ci * T + t];
    }
}

// ---------------- MFMA implicit-GEMM conv ----------------
// Block tile 128(co) x 256(pixels), BK=32, 4 waves (2m x 2n), wave tile 64x128.
// in: [B][Cin][H*W] (fp32 or fp16), wT: [tap][Cin][Cout] fp16.
// OUTMODE: 0 = store f32, 1 = store f16, 2 = atomicAdd f32
template <int INF16, int RELUIN, int OUTMODE, int RELUOUT>
__global__ __launch_bounds__(TPB, 2)
void mfma_conv(const void* __restrict__ in_, const f16* __restrict__ wT,
               void* __restrict__ out_,
               int Cin, int Cout, int H, int W, int ksize, int dil,
               int tapCount, int tapGroup, int kcPerZ,
               long inBStride, long outBStride, int nMtiles, int aspp)
{
    __shared__ f16 Asm[128 * 40];
    __shared__ f16 Bsm[256 * 40];

    const int tid = threadIdx.x;
    const int z  = blockIdx.z;
    const int b  = blockIdx.y;
    const int mt = blockIdx.x % nMtiles;
    const int nt = blockIdx.x / nMtiles;
    const int co0 = mt * 128;
    const int p0  = nt * 256;
    const int HW  = H * W;

    int ks = ksize, dl = dil;
    int tapB, tapE, kcB, kcE;
    long woff = 0, ooff = 0;
    if (aspp) {
        int br, t;
        if (z == 0) { br = 0; t = 0; ks = 1; dl = 1; }
        else { br = 1 + (z - 1) / 9; t = (z - 1) % 9; ks = 3;
               dl = (br == 1) ? 6 : (br == 2 ? 12 : 18); }
        woff = (br == 0) ? 0L : (br == 1 ? 524288L : (br == 2 ? 5242880L : 9961472L));
        tapB = t; tapE = t + 1; kcB = 0; kcE = Cin;
        ooff = (long)br * 278784L;
    } else if (kcPerZ > 0) {
        kcB = z * kcPerZ; kcE = min(Cin, kcB + kcPerZ);
        tapB = 0; tapE = tapCount;
    } else {
        tapB = z * tapGroup; tapE = min(tapCount, tapB + tapGroup);
        kcB = 0; kcE = Cin;
    }

    // staging roles
    const int arow = tid & 127;          // A row (co)
    const int ag0  = (tid >> 7) * 2;     // A k-groups (2 of 4)
    const int prow = tid;                // B row (pixel)
    const int p_lin = p0 + prow;
    const bool pvv = p_lin < HW;
    const int py = pvv ? p_lin / W : 0;
    const int px = pvv ? p_lin - py * W : 0;
    const int y0 = p0 / W;
    const int y1 = min(p0 + 255, HW - 1) / W;
    const bool mvalid = (co0 + arow) < Cout;

    // compute roles
    const int lane = tid & 63;
    const int wid  = tid >> 6;
    const int wm = wid >> 1, wn = wid & 1;
    const int r32 = lane & 31, hh = lane >> 5;

    f32x16 acc[2][4];
#pragma unroll
    for (int i = 0; i < 2; ++i)
#pragma unroll
        for (int j = 0; j < 4; ++j) acc[i][j] = (f32x16)(0.f);

    const int half2 = ks >> 1;
    bool didwork = false;

    for (int tap = tapB; tap < tapE; ++tap) {
        const int ky = tap / ks, kx = tap - ky * ks;
        const int dy = (ky - half2) * dl, dx = (kx - half2) * dl;
        if (y1 + dy < 0 || y0 + dy >= H) continue;   // block-uniform tap skip
        didwork = true;
        const int sy = py + dy, sx = px + dx;
        const bool nv = pvv && ((unsigned)sy < (unsigned)H) && ((unsigned)sx < (unsigned)W);
        const long sidx = (long)sy * W + sx;
        const f16* wTap = wT + woff + (long)tap * ((long)Cin * Cout) + co0 + arow;

        for (int kc = kcB; kc < kcE; kc += 32) {
            __syncthreads();
            // ---- stage A (weights): 2 x f16x8 per thread ----
#pragma unroll
            for (int g = 0; g < 2; ++g) {
                const int kb = kc + (ag0 + g) * 8;
                f16x8 hv;
#pragma unroll
                for (int e = 0; e < 8; ++e) {
                    const int kk = kb + e;
                    hv[e] = (mvalid && kk < kcE) ? wTap[(long)kk * Cout] : (f16)0.f;
                }
                *(f16x8*)&Asm[arow * 40 + (ag0 + g) * 8] = hv;
            }
            // ---- stage B (pixels): 4 x f16x8 per thread ----
#pragma unroll
            for (int g = 0; g < 4; ++g) {
                const int kb = kc + g * 8;
                f16x8 hv;
                if (INF16) {
                    const f16* ip = (const f16*)in_ + (long)b * inBStride + sidx;
#pragma unroll
                    for (int e = 0; e < 8; ++e) {
                        const int kk = kb + e;
                        hv[e] = (nv && kk < kcE) ? ip[(long)kk * HW] : (f16)0.f;
                    }
                } else {
                    const float* ip = (const float*)in_ + (long)b * inBStride + sidx;
#pragma unroll
                    for (int e = 0; e < 8; ++e) {
                        const int kk = kb + e;
                        float x = (nv && kk < kcE) ? ip[(long)kk * HW] : 0.f;
                        if (RELUIN) x = fmaxf(x, 0.f);
                        hv[e] = (f16)x;
                    }
                }
                *(f16x8*)&Bsm[prow * 40 + g * 8] = hv;
            }
            __syncthreads();
            // ---- compute: 16 MFMA per wave per K-step ----
            const f16* Ab = &Asm[(wm * 64 + r32) * 40 + hh * 8];
            const f16* Bb = &Bsm[(wn * 128 + r32) * 40 + hh * 8];
#pragma unroll
            for (int kh = 0; kh < 2; ++kh) {
                const f16x8 a0 = *(const f16x8*)(Ab + kh * 16);
                const f16x8 a1 = *(const f16x8*)(Ab + 32 * 40 + kh * 16);
                const f16x8 b0 = *(const f16x8*)(Bb + kh * 16);
                const f16x8 b1 = *(const f16x8*)(Bb + 32 * 40 + kh * 16);
                const f16x8 b2 = *(const f16x8*)(Bb + 64 * 40 + kh * 16);
                const f16x8 b3 = *(const f16x8*)(Bb + 96 * 40 + kh * 16);
                acc[0][0] = __builtin_amdgcn_mfma_f32_32x32x16_f16(a0, b0, acc[0][0], 0, 0, 0);
                acc[0][1] = __builtin_amdgcn_mfma_f32_32x32x16_f16(a0, b1, acc[0][1], 0, 0, 0);
                acc[0][2] = __builtin_amdgcn_mfma_f32_32x32x16_f16(a0, b2, acc[0][2], 0, 0, 0);
                acc[0][3] = __builtin_amdgcn_mfma_f32_32x32x16_f16(a0, b3, acc[0][3], 0, 0, 0);
                acc[1][0] = __builtin_amdgcn_mfma_f32_32x32x16_f16(a1, b0, acc[1][0], 0, 0, 0);
                acc[1][1] = __builtin_amdgcn_mfma_f32_32x32x16_f16(a1, b1, acc[1][1], 0, 0, 0);
                acc[1][2] = __builtin_amdgcn_mfma_f32_32x32x16_f16(a1, b2, acc[1][2], 0, 0, 0);
                acc[1][3] = __builtin_amdgcn_mfma_f32_32x32x16_f16(a1, b3, acc[1][3], 0, 0, 0);
            }
        }
    }

    if (OUTMODE == 2 && !didwork) return;  // all taps skipped -> zero contribution

    const long outB = (long)b * outBStride + ooff;
#pragma unroll
    for (int mi = 0; mi < 2; ++mi)
#pragma unroll
    for (int ni = 0; ni < 4; ++ni)
#pragma unroll
    for (int j = 0; j < 16; ++j) {
        const int m = wm * 64 + mi * 32 + 4 * hh + (j & 3) + 8 * (j >> 2);
        const int n = wn * 128 + ni * 32 + r32;
        const int co = co0 + m;
        const int p  = p0 + n;
        if (co < Cout && p < HW) {
            float v = acc[mi][ni][j];
            if (RELUOUT) v = fmaxf(v, 0.f);
            if (OUTMODE == 0)      ((float*)out_)[outB + (long)co * HW + p] = v;
            else if (OUTMODE == 1) ((f16*)out_)[outB + (long)co * HW + p] = (f16)v;
            else atomicAdd(&((float*)out_)[outB + (long)co * HW + p], v);
        }
    }
}

// ---------------- global average pool ----------------
__global__ __launch_bounds__(TPB)
void gpool_k(const float* __restrict__ in, float* __restrict__ gp, int HW, float inv)
{
    const int bc = blockIdx.x;
    const float* p = in + (size_t)bc * HW;
    float s = 0.f;
    for (int i = threadIdx.x; i < HW; i += TPB) s += p[i];
#pragma unroll
    for (int off = 32; off > 0; off >>= 1) s += __shfl_down(s, off, 64);
    __shared__ float red[4];
    if ((threadIdx.x & 63) == 0) red[threadIdx.x >> 6] = s;
    __syncthreads();
    if (threadIdx.x == 0) gp[bc] = (red[0] + red[1] + red[2] + red[3]) * inv;
}

// gpr[b][c] = relu( sum_k poolT[k][c] * gp[b][k] )
__global__ __launch_bounds__(TPB)
void poolconv_k(const float* __restrict__ poolT, const float* __restrict__ gp,
                float* __restrict__ gpr)
{
    const int b = blockIdx.x, c = threadIdx.x;
    const float* g = gp + (size_t)b * 2048;
    float s = 0.f;
    for (int k = 0; k < 2048; ++k) s = fmaf(poolT[(size_t)k * 256 + c], g[k], s);
    gpr[b * 256 + c] = fmaxf(s, 0.f);
}

// gpc[b][c] = sum_j aprojT[1024+j][c] * gpr[b][j]
__global__ __launch_bounds__(TPB)
void gpc_k(const float* __restrict__ aprojT, const float* __restrict__ gpr,
           float* __restrict__ gpc)
{
    const int b = blockIdx.x, c = threadIdx.x;
    const float* g = gpr + (size_t)b * 256;
    const float* w = aprojT + (size_t)1024 * 256;
    float s = 0.f;
    for (int j = 0; j < 256; ++j) s = fmaf(w[(size_t)j * 256 + c], g[j], s);
    gpc[b * 256 + c] = s;
}

// YB[b][c][p] = gpc[b][c]   (bias prefill for aproj split-K atomics)
__global__ __launch_bounds__(TPB)
void biasfill_k(const float* __restrict__ gpc, float* __restrict__ yb)
{
    const int idx = blockIdx.x * TPB + threadIdx.x;
    if (idx >= 2 * 256 * 1089) return;
    const int c = (idx / 1089) & 255;
    const int b = idx / (256 * 1089);
    yb[idx] = gpc[b * 256 + c];
}

// ---------------- bilinear upsample (relu(src) then lerp) -> OT dst ----------------
template <typename OT, int RELU>
__global__ __launch_bounds__(TPB)
void upsample_k(const float* __restrict__ src, OT* __restrict__ dst,
                int C, int inH, int inW, int outH, int outW,
                long dstBStride, int dstChOff, int B)
{
    const int idx = blockIdx.x * TPB + threadIdx.x;
    const int total = B * C * outH * outW;
    if (idx >= total) return;
    const int ox = idx % outW;
    int r = idx / outW;
    const int oy = r % outH; r /= outH;
    const int c = r % C;
    const int b = r / C;
    const float sx = (ox + 0.5f) * ((float)inW / (float)outW) - 0.5f;
    const float sy = (oy + 0.5f) * ((float)inH / (float)outH) - 0.5f;
    int ix0 = (int)floorf(sx), iy0 = (int)floorf(sy);
    const float fx = sx - ix0, fy = sy - iy0;
    int ix1 = min(inW - 1, max(0, ix0 + 1)); ix0 = min(inW - 1, max(0, ix0));
    int iy1 = min(inH - 1, max(0, iy0 + 1)); iy0 = min(inH - 1, max(0, iy0));
    const float* s = src + ((size_t)b * C + c) * inH * inW;
    float v00 = s[iy0 * inW + ix0], v01 = s[iy0 * inW + ix1];
    float v10 = s[iy1 * inW + ix0], v11 = s[iy1 * inW + ix1];
    if (RELU) {
        v00 = fmaxf(v00, 0.f); v01 = fmaxf(v01, 0.f);
        v10 = fmaxf(v10, 0.f); v11 = fmaxf(v11, 0.f);
    }
    const float v0 = v00 + (v01 - v00) * fx;
    const float v1 = v10 + (v11 - v10) * fx;
    dst[(size_t)b * dstBStride + (size_t)(dstChOff + c) * outH * outW + (size_t)oy * outW + ox]
        = (OT)(v0 + (v1 - v0) * fy);
}

// ---------------- cw2 1x1 conv, relu on input ----------------
template <int NC>
__global__ __launch_bounds__(TPB)
void conv1x1_small(const float* __restrict__ in, const float* __restrict__ wT,
                   const float* __restrict__ bias, float* __restrict__ out, int HW)
{
    __shared__ float wsm[256 * NC];
    const int tid = threadIdx.x;
    for (int l = tid; l < 256 * NC; l += TPB) wsm[l] = wT[l];
    __syncthreads();
    const int b = blockIdx.y;
    const int p = blockIdx.x * TPB + tid;
    if (p >= HW) return;
    const float* inB = in + (size_t)b * 256 * HW + p;
    float acc[NC];
#pragma unroll
    for (int c = 0; c < NC; ++c) acc[c] = 0.f;
    for (int k = 0; k < 256; ++k) {
        const float x = fmaxf(inB[(size_t)k * HW], 0.f);
#pragma unroll
        for (int c = 0; c < NC; ++c) acc[c] = fmaf(wsm[k * NC + c], x, acc[c]);
    }
    float* oB = out + (size_t)b * NC * HW + p;
#pragma unroll
    for (int c = 0; c < NC; ++c) oB[(size_t)c * HW] = acc[c] + bias[c];
}

// ---------------- final: 129->513 bilinear + logits + NHWC features ----------------
template <int NC>
__global__ __launch_bounds__(TPB)
void final_k(const float* __restrict__ x, float* __restrict__ logits,
             float* __restrict__ feats)
{
    const int idx = blockIdx.x * TPB + threadIdx.x;
    const long HW = 513L * 513L;
    if (idx >= 2 * 513 * 513) return;
    const int ox = idx % 513;
    int r = idx / 513;
    const int oy = r % 513;
    const int b = r / 513;
    const float sc = 129.0f / 513.0f;
    const float sx = (ox + 0.5f) * sc - 0.5f;
    const float sy = (oy + 0.5f) * sc - 0.5f;
    int ix0 = (int)floorf(sx), iy0 = (int)floorf(sy);
    const float fx = sx - ix0, fy = sy - iy0;
    int ix1 = min(128, max(0, ix0 + 1)); ix0 = min(128, max(0, ix0));
    int iy1 = min(128, max(0, iy0 + 1)); iy0 = min(128, max(0, iy0));
    const float* xb = x + (size_t)b * NC * 16641;
    const int i00 = iy0 * 129 + ix0, i01 = iy0 * 129 + ix1;
    const int i10 = iy1 * 129 + ix0, i11 = iy1 * 129 + ix1;
    float v[NC];
    float ss = 0.f;
#pragma unroll
    for (int c = 0; c < NC; ++c) {
        const float* s = xb + (size_t)c * 16641;
        const float a0 = s[i00] + (s[i01] - s[i00]) * fx;
        const float a1 = s[i10] + (s[i11] - s[i10]) * fx;
        const float vv = a0 + (a1 - a0) * fy;
        v[c] = vv;
        ss = fmaf(vv, vv, ss);
    }
    const long pix = (long)oy * 513 + ox;
#pragma unroll
    for (int c = 0; c < NC; ++c)
        logits[((size_t)b * NC + c) * HW + pix] = fmaf(6.f, v[c], -ss - 9.f);
    float* f = feats + ((size_t)b * HW + pix) * NC;
#pragma unroll
    for (int c = 0; c < NC; ++c) f[c] = v[c];
}

__global__ void centers_k(float* __restrict__ c0, float* __restrict__ c1)
{
    const int t = blockIdx.x * 64 + threadIdx.x;
    if (t < 256) c0[t] = (t / 16 == t % 16) ? 3.f : 0.f;
    const int u = t - 256;
    if (u >= 0 && u < 289) c1[u] = (u / 17 == u % 17) ? 3.f : 0.f;
}

// ---------------- host ----------------
extern "C" void kernel_launch(void* const* d_in, const int* in_sizes, int n_in,
                              void* d_out, int out_size, void* d_ws, size_t ws_size,
                              hipStream_t stream)
{
    const float* low_level = (const float*)d_in[0];
    const float* aspp_in   = (const float*)d_in[1];
    float* ws = (float*)d_ws;
    float* o  = (float*)d_out;

    // ---- ws arenas ----
    f16*   ASPPW   = (f16*)ws;                       // 14,680,064 halves
    f16*   APROJT16= ASPPW + 14680064;               //    327,680 halves
    f16*   CW1T    = APROJT16 + 327680;              //    700,416 halves
    f16*   PWT16   = CW1T + 700416;                  //     12,288 halves
    float* CW2T    = ws + 7860224;                   //      4,608
    float* POOLT32 = CW2T + 4608;                    //    524,288
    float* APROJT32= POOLT32 + 524288;               //    327,680
    float* GP      = APROJT32 + 327680;              //      4,096
    float* GPR     = GP + 4096;                      //        512
    float* GPC     = GPR + 512;                      //        512
    float* BRacc   = GPC + 512;                      //  2,230,272
    float* YB      = BRacc + 2230272;                //    557,568
    f16*   CC      = (f16*)(YB + 557568);            // 10,117,728 halves
    float* C1O     = YB + 557568 + 5058864;          //  8,520,192
    float* XB      = C1O + 8520192;                  //    565,794

    const long L0o = 0, L1o = 8421408, C0o = 17369154, C1oo = 17369410,
               F0o = 17369699, F1o = 25791107;

    gpool_k<<<4096, TPB, 0, stream>>>(aspp_in, GP, 1089, 1.0f / 1089.0f);

    for (int h = 0; h < 2; ++h) {
        const float* pw    = (const float*)d_in[2 + h * 10 + 0];
        const float* w0    = (const float*)d_in[2 + h * 10 + 1];
        const float* w1    = (const float*)d_in[2 + h * 10 + 2];
        const float* w2    = (const float*)d_in[2 + h * 10 + 3];
        const float* w3    = (const float*)d_in[2 + h * 10 + 4];
        const float* poolw = (const float*)d_in[2 + h * 10 + 5];
        const float* aproj = (const float*)d_in[2 + h * 10 + 6];
        const float* cw1   = (const float*)d_in[2 + h * 10 + 7];
        const float* cw2   = (const float*)d_in[2 + h * 10 + 8];
        const float* cb2   = (const float*)d_in[2 + h * 10 + 9];

        hipMemsetAsync(BRacc, 0, 2230272 * sizeof(float), stream);
        hipMemsetAsync(C1O,   0, 8520192 * sizeof(float), stream);

        // pooled branch -> per-(b,c) bias of aproj, prefilled into YB
        wtrans_k<float><<<dim3(64, 8), TPB, 0, stream>>>(poolw, POOLT32, 256, 2048, 1);
        wtrans_k<float><<<dim3(40, 8), TPB, 0, stream>>>(aproj, APROJT32, 256, 1280, 1);
        poolconv_k<<<2, TPB, 0, stream>>>(POOLT32, GP, GPR);
        gpc_k<<<2, TPB, 0, stream>>>(APROJT32, GPR, GPC);
        biasfill_k<<<2178, TPB, 0, stream>>>(GPC, YB);

        // fp16 weight transposes
        wtrans_k<f16><<<dim3(64, 8), TPB, 0, stream>>>(w0, ASPPW,           256, 2048, 1);
        wtrans_k<f16><<<dim3(64, 8), TPB, 0, stream>>>(w1, ASPPW + 524288,  256, 2048, 9);
        wtrans_k<f16><<<dim3(64, 8), TPB, 0, stream>>>(w2, ASPPW + 5242880, 256, 2048, 9);
        wtrans_k<f16><<<dim3(64, 8), TPB, 0, stream>>>(w3, ASPPW + 9961472, 256, 2048, 9);
        wtrans_k<f16><<<dim3(40, 8), TPB, 0, stream>>>(aproj, APROJT16, 256, 1280, 1);
        wtrans_k<f16><<<dim3(10, 8), TPB, 0, stream>>>(cw1, CW1T, 256, 304, 9);
        wtrans_k<f16><<<dim3(8, 2), TPB, 0, stream>>>(pw, PWT16, 48, 256, 1);

        // fused ASPP (z = 28 branch-taps), atomic into zeroed BRacc
        mfma_conv<0, 0, 2, 0><<<dim3(10, 2, 28), TPB, 0, stream>>>(
            aspp_in, ASPPW, BRacc, 2048, 256, 33, 33, 3, 1,
            1, 1, 0, 2048L * 1089, 1024L * 1089, 2, 1);
        // aproj 1x1 (relu-in from BRacc), split-K z=8, atomic into bias-filled YB
        mfma_conv<0, 1, 2, 0><<<dim3(10, 2, 8), TPB, 0, stream>>>(
            BRacc, APROJT16, YB, 1024, 256, 33, 33, 1, 1,
            1, 1, 128, 1024L * 1089, 256L * 1089, 2, 0);
        // low-level 1x1 (48ch, relu) -> CC channels 0..47 (fp16)
        mfma_conv<0, 0, 1, 1><<<dim3(66, 2, 1), TPB, 0, stream>>>(
            low_level, PWT16, CC, 256, 48, 129, 129, 1, 1,
            1, 1, 0, 256L * 16641, 304L * 16641, 1, 0);
        // upsample 33->129 with relu -> CC channels 48..303 (fp16)
        upsample_k<f16, 1><<<33282, TPB, 0, stream>>>(YB, CC,
            256, 33, 33, 129, 129, 304L * 16641, 48, 2);
        // cw1 3x3 (304->256), 2 tap-groups, atomic into zeroed C1O (relu deferred)
        mfma_conv<1, 0, 2, 0><<<dim3(132, 2, 2), TPB, 0, stream>>>(
            CC, CW1T, C1O, 304, 256, 129, 129, 3, 1,
            9, 5, 0, 304L * 16641, 256L * 16641, 2, 0);

        if (h == 0) {
            wtrans_k<float><<<dim3(8, 1), TPB, 0, stream>>>(cw2, CW2T, 16, 256, 1);
            conv1x1_small<16><<<dim3(66, 2), TPB, 0, stream>>>(C1O, CW2T, cb2, XB, 16641);
            final_k<16><<<2057, TPB, 0, stream>>>(XB, o + L0o, o + F0o);
        } else {
            wtrans_k<float><<<dim3(8, 1), TPB, 0, stream>>>(cw2, CW2T, 17, 256, 1);
            conv1x1_small<17><<<dim3(66, 2), TPB, 0, stream>>>(C1O, CW2T, cb2, XB, 16641);
            final_k<17><<<2057, TPB, 0, stream>>>(XB, o + L1o, o + F1o);
        }
    }
    centers_k<<<9, 64, 0, stream>>>(o + C0o, o + C1oo);
}

// Round 3
// 1697.159 us; speedup vs baseline: 6.0130x; 2.4114x over previous
//
#include <hip/hip_runtime.h>

#define TPB 256

typedef _Float16 f16;
typedef __attribute__((ext_vector_type(8))) _Float16 f16x8;
typedef __attribute__((ext_vector_type(16))) float f32x16;

#define GLD_LDS(g, l) __builtin_amdgcn_global_load_lds( \
    (const __attribute__((address_space(1))) void*)(g), \
    (__attribute__((address_space(3))) void*)(l), 16, 0, 0)

// ---------- weight pack: w[Cout][CinSrc][T] f32 -> Wp[t][kb][coP][64] f16 ----------
// k >= CinUse or co >= Cout -> 0.  Grid: (KB, coP/16).
__global__ __launch_bounds__(TPB)
void packw_k(const float* __restrict__ w, f16* __restrict__ dst,
             int Cout, int CinUse, int CinSrc, int T, int coP, int KB)
{
    __shared__ float tile[16 * 577];
    const int RL = 64 * T;
    const int kb = blockIdx.x;
    const int coT = blockIdx.y;
    const int tid = threadIdx.x;
    const int n = 16 * RL;
    for (int idx = tid; idx < n; idx += TPB) {
        const int row = idx / RL;
        const int j = idx - row * RL;
        const int co = coT * 16 + row;
        const int k = kb * 64 + j / T;
        float v = 0.f;
        if (co < Cout && k < CinUse)
            v = w[((long)co * CinSrc + kb * 64) * T + j];
        tile[row * 577 + j] = v;
    }
    __syncthreads();
    const int nst = 128 * T;
    for (int idx = tid; idx < nst; idx += TPB) {
        const int g = idx & 7;
        const int t = (idx >> 3) % T;
        const int co = idx / (8 * T);
        f16x8 hv;
#pragma unroll
        for (int e = 0; e < 8; ++e)
            hv[e] = (f16)tile[co * 577 + (g * 8 + e) * T + t];
        *(f16x8*)&dst[(((long)t * KB + kb) * coP + coT * 16 + co) * 64 + g * 8] = hv;
    }
}

// ---------- transpose-cvt: src[B][C][HW] (f32 or f16) -> dst[B][HW][ldk] f16 at colOff ----------
template <typename ST, int RELU>
__global__ __launch_bounds__(TPB)
void tc_k(const ST* __restrict__ src, f16* __restrict__ dst,
          int C, int HW, int ldk, int colOff)
{
    __shared__ float t32[32 * 33];
    const int pT = blockIdx.x, cT = blockIdx.y, bb = blockIdx.z;
    const int tid = threadIdx.x;
#pragma unroll
    for (int pass = 0; pass < 4; ++pass) {
        const int ch = tid / 32 + pass * 8;
        const int px = tid % 32;
        const int c = cT * 32 + ch, p = pT * 32 + px;
        float v = 0.f;
        if (c < C && p < HW) v = (float)src[((long)bb * C + c) * HW + p];
        if (RELU) v = fmaxf(v, 0.f);
        t32[ch * 33 + px] = v;
    }
    __syncthreads();
#pragma unroll
    for (int pass = 0; pass < 4; ++pass) {
        const int px = tid / 32 + pass * 8;
        const int ch = tid % 32;
        const int p = pT * 32 + px, c = cT * 32 + ch;
        if (p < HW && c < C)
            dst[((long)bb * HW + p) * ldk + colOff + c] = (f16)t32[ch * 33 + px];
    }
}

// ---------- MFMA implicit-GEMM conv, global_load_lds staging ----------
// X: [B][NP][Cinp] f16 pixel-major. Wp: [t][kb][coP][64] f16.
// Block 128(co) x 256(px), BK=64, 4 waves 2x2, wave tile 64x128.
// OUTMODE: 0=f32 store, 1=f16 store, 2=atomicAdd f32.
template <int OUTMODE, int ASPPZ, int ZMODE, int RELUOUT>
__global__ __launch_bounds__(TPB, 2)
void mconv(const f16* __restrict__ X, const f16* __restrict__ Wp,
           const f16* __restrict__ guard, void* __restrict__ out_,
           int Cinp, int Cout, int H, int W, int ks, int dil,
           int KBtot, int zKb, long outBStride, int nMtiles, int coP)
{
    __shared__ f16 Asm[128 * 64];
    __shared__ f16 Bsm[256 * 64];
    const int tid = threadIdx.x;
    const int b = blockIdx.y;
    const int mt = blockIdx.x % nMtiles, nt = blockIdx.x / nMtiles;
    const int co0 = mt * 128, p0 = nt * 256;
    const int NP = H * W;

    int tap = 0, kbB = 0, kbE = KBtot, dl = dil, kss = ks;
    long woff = 0, ooff = 0;
    if (ASPPZ) {
        const int z = blockIdx.z;
        int br;
        if (z == 0) { br = 0; tap = 0; kss = 1; dl = 1; }
        else { br = 1 + (z - 1) / 9; tap = (z - 1) % 9; kss = 3;
               dl = (br == 1) ? 6 : (br == 2 ? 12 : 18); }
        woff = (br == 0) ? 0L : (br == 1 ? 524288L : (br == 2 ? 5242880L : 9961472L));
        ooff = (long)br * 278784L;
    } else if (ZMODE == 1) {
        tap = blockIdx.z;
    } else if (ZMODE == 2) {
        kbB = blockIdx.z * zKb; kbE = min(KBtot, kbB + zKb);
    }
    const int half = kss >> 1;
    const int ky = tap / kss, kx = tap - ky * kss;
    const int dy = (ky - half) * dl, dx = (kx - half) * dl;
    {
        const int y0 = p0 / W, y1 = min(p0 + 255, NP - 1) / W;
        if (y1 + dy < 0 || y0 + dy >= H) return;  // only reachable for atomic tap modes
    }

    // ---- B source row pointers (8 rounds x 32 rows) ----
    const int qq = tid & 7;
    const f16* srcB[8];
#pragma unroll
    for (int r = 0; r < 8; ++r) {
        const int row = r * 32 + (tid >> 3);
        const int p = p0 + row;
        bool v = p < NP;
        const int py = v ? p / W : 0;
        const int px = v ? p - py * W : 0;
        const int sy = py + dy, sx = px + dx;
        v = v && ((unsigned)sy < (unsigned)H) && ((unsigned)sx < (unsigned)W);
        const int swz = (qq ^ (row & 7)) << 3;
        srcB[r] = v ? (X + ((long)b * NP + (long)sy * W + sx) * Cinp + swz)
                    : (guard + swz);
    }
    // ---- A source offsets (4 rounds x 32 rows) ----
    int aoff[4];
#pragma unroll
    for (int r = 0; r < 4; ++r) {
        const int co = r * 32 + (tid >> 3);
        aoff[r] = co * 64 + ((qq ^ (co & 7)) << 3);
    }
    const f16* Wbase = Wp + woff + (long)tap * KBtot * coP * 64 + (long)co0 * 64;

    const int lane = tid & 63, wid = tid >> 6;
    const int wm = wid >> 1, wn = wid & 1;
    const int r32 = lane & 31, hh = lane >> 5;
    const int rA0 = wm * 64 + r32;
    const int key = r32 & 7;

    f32x16 acc[2][4];
#pragma unroll
    for (int i = 0; i < 2; ++i)
#pragma unroll
        for (int j = 0; j < 4; ++j) acc[i][j] = (f32x16)(0.f);

    char* AsmB = (char*)Asm;
    char* BsmB = (char*)Bsm;
    const int wofs = wid * 1024;

    for (int kb = kbB; kb < kbE; ++kb) {
        __syncthreads();
        const f16* wsrc = Wbase + (long)kb * coP * 64;
#pragma unroll
        for (int r = 0; r < 4; ++r)
            GLD_LDS(wsrc + aoff[r], AsmB + r * 4096 + wofs);
#pragma unroll
        for (int r = 0; r < 8; ++r)
            GLD_LDS(srcB[r] + (long)kb * 64, BsmB + r * 4096 + wofs);
        __syncthreads();
#pragma unroll
        for (int kh = 0; kh < 4; ++kh) {
            const int g = (((kh * 2 + hh) ^ key) << 4);
            const f16x8 a0 = *(const f16x8*)(AsmB + rA0 * 128 + g);
            const f16x8 a1 = *(const f16x8*)(AsmB + (rA0 + 32) * 128 + g);
            const int bBase = (wn * 128 + r32) * 128 + g;
            const f16x8 b0 = *(const f16x8*)(BsmB + bBase);
            const f16x8 b1 = *(const f16x8*)(BsmB + bBase + 32 * 128);
            const f16x8 b2 = *(const f16x8*)(BsmB + bBase + 64 * 128);
            const f16x8 b3 = *(const f16x8*)(BsmB + bBase + 96 * 128);
            acc[0][0] = __builtin_amdgcn_mfma_f32_32x32x16_f16(a0, b0, acc[0][0], 0, 0, 0);
            acc[0][1] = __builtin_amdgcn_mfma_f32_32x32x16_f16(a0, b1, acc[0][1], 0, 0, 0);
            acc[0][2] = __builtin_amdgcn_mfma_f32_32x32x16_f16(a0, b2, acc[0][2], 0, 0, 0);
            acc[0][3] = __builtin_amdgcn_mfma_f32_32x32x16_f16(a0, b3, acc[0][3], 0, 0, 0);
            acc[1][0] = __builtin_amdgcn_mfma_f32_32x32x16_f16(a1, b0, acc[1][0], 0, 0, 0);
            acc[1][1] = __builtin_amdgcn_mfma_f32_32x32x16_f16(a1, b1, acc[1][1], 0, 0, 0);
            acc[1][2] = __builtin_amdgcn_mfma_f32_32x32x16_f16(a1, b2, acc[1][2], 0, 0, 0);
            acc[1][3] = __builtin_amdgcn_mfma_f32_32x32x16_f16(a1, b3, acc[1][3], 0, 0, 0);
        }
    }

    const long outB = (long)b * outBStride + ooff;
#pragma unroll
    for (int mi = 0; mi < 2; ++mi)
#pragma unroll
    for (int ni = 0; ni < 4; ++ni)
#pragma unroll
    for (int j = 0; j < 16; ++j) {
        const int m = wm * 64 + mi * 32 + 4 * hh + (j & 3) + 8 * (j >> 2);
        const int n = wn * 128 + ni * 32 + r32;
        const int co = co0 + m;
        const int p = p0 + n;
        if (co < Cout && p < NP) {
            float v = acc[mi][ni][j];
            if (RELUOUT) v = fmaxf(v, 0.f);
            if (OUTMODE == 0)      ((float*)out_)[outB + (long)co * NP + p] = v;
            else if (OUTMODE == 1) ((f16*)out_)[outB + (long)co * NP + p] = (f16)v;
            else atomicAdd(&((float*)out_)[outB + (long)co * NP + p], v);
        }
    }
}

// ---------- small helpers (unchanged from R2) ----------
__global__ __launch_bounds__(TPB)
void wtrans_f32(const float* __restrict__ w, float* __restrict__ wT,
                int Cout, int Cin, int T)
{
    __shared__ float tile[32 * (32 * 9 + 1)];
    const int rowlen = 32 * T + 1;
    const int co0 = blockIdx.y * 32;
    const int ci0 = blockIdx.x * 32;
    const int n = 32 * 32 * T;
    const int tid = threadIdx.x;
    for (int l = tid; l < n; l += TPB) {
        int co = l / (32 * T);
        int rem = l - co * (32 * T);
        int ci = rem / T;
        float v = 0.f;
        if (co0 + co < Cout && ci0 + ci < Cin)
            v = w[(size_t)(co0 + co) * Cin * T + (size_t)ci0 * T + rem];
        tile[co * rowlen + rem] = v;
    }
    __syncthreads();
    for (int l = tid; l < n; l += TPB) {
        int co = l & 31;
        int ci = (l >> 5) & 31;
        int t = l >> 10;
        if (co0 + co < Cout && ci0 + ci < Cin)
            wT[((size_t)t * Cin + (ci0 + ci)) * Cout + (co0 + co)] = tile[co * rowlen + ci * T + t];
    }
}

__global__ __launch_bounds__(TPB)
void gpool_k(const float* __restrict__ in, float* __restrict__ gp, int HW, float inv)
{
    const int bc = blockIdx.x;
    const float* p = in + (size_t)bc * HW;
    float s = 0.f;
    for (int i = threadIdx.x; i < HW; i += TPB) s += p[i];
#pragma unroll
    for (int off = 32; off > 0; off >>= 1) s += __shfl_down(s, off, 64);
    __shared__ float red[4];
    if ((threadIdx.x & 63) == 0) red[threadIdx.x >> 6] = s;
    __syncthreads();
    if (threadIdx.x == 0) gp[bc] = (red[0] + red[1] + red[2] + red[3]) * inv;
}

__global__ __launch_bounds__(TPB)
void poolconv_k(const float* __restrict__ poolT, const float* __restrict__ gp,
                float* __restrict__ gpr)
{
    const int b = blockIdx.x, c = threadIdx.x;
    const float* g = gp + (size_t)b * 2048;
    float s = 0.f;
    for (int k = 0; k < 2048; ++k) s = fmaf(poolT[(size_t)k * 256 + c], g[k], s);
    gpr[b * 256 + c] = fmaxf(s, 0.f);
}

__global__ __launch_bounds__(TPB)
void gpc_k(const float* __restrict__ aprojT, const float* __restrict__ gpr,
           float* __restrict__ gpc)
{
    const int b = blockIdx.x, c = threadIdx.x;
    const float* g = gpr + (size_t)b * 256;
    const float* w = aprojT + (size_t)1024 * 256;
    float s = 0.f;
    for (int j = 0; j < 256; ++j) s = fmaf(w[(size_t)j * 256 + c], g[j], s);
    gpc[b * 256 + c] = s;
}

__global__ __launch_bounds__(TPB)
void biasfill_k(const float* __restrict__ gpc, float* __restrict__ yb)
{
    const int idx = blockIdx.x * TPB + threadIdx.x;
    if (idx >= 2 * 256 * 1089) return;
    const int c = (idx / 1089) & 255;
    const int b = idx / (256 * 1089);
    yb[idx] = gpc[b * 256 + c];
}

// ---------- upsample 33->129 from pixel-major YBX, writes CCX cols 48..303 ----------
__global__ __launch_bounds__(TPB)
void ups2_k(const f16* __restrict__ ybx, f16* __restrict__ ccx)
{
    const int idx = blockIdx.x * TPB + threadIdx.x;
    if (idx >= 2 * 16641 * 32) return;
    const int cg = idx & 31;
    const int p = (idx >> 5) % 16641;
    const int b = idx / (16641 * 32);
    const int oy = p / 129, ox = p % 129;
    const float sc = 33.0f / 129.0f;
    const float sx = (ox + 0.5f) * sc - 0.5f;
    const float sy = (oy + 0.5f) * sc - 0.5f;
    int ix0 = (int)floorf(sx), iy0 = (int)floorf(sy);
    const float fx = sx - ix0, fy = sy - iy0;
    int ix1 = min(32, max(0, ix0 + 1)); ix0 = min(32, max(0, ix0));
    int iy1 = min(32, max(0, iy0 + 1)); iy0 = min(32, max(0, iy0));
    const f16* base = ybx + (long)b * 1089 * 256 + cg * 8;
    const f16x8 v00 = *(const f16x8*)(base + ((long)iy0 * 33 + ix0) * 256);
    const f16x8 v01 = *(const f16x8*)(base + ((long)iy0 * 33 + ix1) * 256);
    const f16x8 v10 = *(const f16x8*)(base + ((long)iy1 * 33 + ix0) * 256);
    const f16x8 v11 = *(const f16x8*)(base + ((long)iy1 * 33 + ix1) * 256);
    f16x8 r;
#pragma unroll
    for (int e = 0; e < 8; ++e) {
        const float a0 = (float)v00[e] + ((float)v01[e] - (float)v00[e]) * fx;
        const float a1 = (float)v10[e] + ((float)v11[e] - (float)v10[e]) * fx;
        r[e] = (f16)(a0 + (a1 - a0) * fy);
    }
    *(f16x8*)(ccx + ((long)b * 16641 + p) * 320 + 48 + cg * 8) = r;
}

// ---------- cw2 1x1 conv (relu on input) ----------
template <int NC>
__global__ __launch_bounds__(TPB)
void conv1x1_small(const float* __restrict__ in, const float* __restrict__ wT,
                   const float* __restrict__ bias, float* __restrict__ out, int HW)
{
    __shared__ float wsm[256 * NC];
    const int tid = threadIdx.x;
    for (int l = tid; l < 256 * NC; l += TPB) wsm[l] = wT[l];
    __syncthreads();
    const int b = blockIdx.y;
    const int p = blockIdx.x * TPB + tid;
    if (p >= HW) return;
    const float* inB = in + (size_t)b * 256 * HW + p;
    float acc[NC];
#pragma unroll
    for (int c = 0; c < NC; ++c) acc[c] = 0.f;
    for (int k = 0; k < 256; ++k) {
        const float x = fmaxf(inB[(size_t)k * HW], 0.f);
#pragma unroll
        for (int c = 0; c < NC; ++c) acc[c] = fmaf(wsm[k * NC + c], x, acc[c]);
    }
    float* oB = out + (size_t)b * NC * HW + p;
#pragma unroll
    for (int c = 0; c < NC; ++c) oB[(size_t)c * HW] = acc[c] + bias[c];
}

// ---------- final: 129->513 bilinear + logits + NHWC features ----------
template <int NC>
__global__ __launch_bounds__(TPB)
void final_k(const float* __restrict__ x, float* __restrict__ logits,
             float* __restrict__ feats)
{
    const int idx = blockIdx.x * TPB + threadIdx.x;
    const long HW = 513L * 513L;
    if (idx >= 2 * 513 * 513) return;
    const int ox = idx % 513;
    int r = idx / 513;
    const int oy = r % 513;
    const int b = r / 513;
    const float sc = 129.0f / 513.0f;
    const float sx = (ox + 0.5f) * sc - 0.5f;
    const float sy = (oy + 0.5f) * sc - 0.5f;
    int ix0 = (int)floorf(sx), iy0 = (int)floorf(sy);
    const float fx = sx - ix0, fy = sy - iy0;
    int ix1 = min(128, max(0, ix0 + 1)); ix0 = min(128, max(0, ix0));
    int iy1 = min(128, max(0, iy0 + 1)); iy0 = min(128, max(0, iy0));
    const float* xb = x + (size_t)b * NC * 16641;
    const int i00 = iy0 * 129 + ix0, i01 = iy0 * 129 + ix1;
    const int i10 = iy1 * 129 + ix0, i11 = iy1 * 129 + ix1;
    float v[NC];
    float ss = 0.f;
#pragma unroll
    for (int c = 0; c < NC; ++c) {
        const float* s = xb + (size_t)c * 16641;
        const float a0 = s[i00] + (s[i01] - s[i00]) * fx;
        const float a1 = s[i10] + (s[i11] - s[i10]) * fx;
        const float vv = a0 + (a1 - a0) * fy;
        v[c] = vv;
        ss = fmaf(vv, vv, ss);
    }
    const long pix = (long)oy * 513 + ox;
#pragma unroll
    for (int c = 0; c < NC; ++c)
        logits[((size_t)b * NC + c) * HW + pix] = fmaf(6.f, v[c], -ss - 9.f);
    float* f = feats + ((size_t)b * HW + pix) * NC;
#pragma unroll
    for (int c = 0; c < NC; ++c) f[c] = v[c];
}

__global__ void centers_k(float* __restrict__ c0, float* __restrict__ c1)
{
    const int t = blockIdx.x * 64 + threadIdx.x;
    if (t < 256) c0[t] = (t / 16 == t % 16) ? 3.f : 0.f;
    const int u = t - 256;
    if (u >= 0 && u < 289) c1[u] = (u / 17 == u % 17) ? 3.f : 0.f;
}

// ---------------- host ----------------
extern "C" void kernel_launch(void* const* d_in, const int* in_sizes, int n_in,
                              void* d_out, int out_size, void* d_ws, size_t ws_size,
                              hipStream_t stream)
{
    const float* low_level = (const float*)d_in[0];
    const float* aspp_in   = (const float*)d_in[1];
    float* ws = (float*)d_ws;
    float* o  = (float*)d_out;

    // ---- ws layout (floats) ----
    f16*   GUARD   = (f16*)(ws + 0);                  //  4,096 fl (zeros)
    float* AR      = ws + 4096;                       //  8,520,192 fl: Apack (7.34M fl) then C1O
    f16*   Apack   = (f16*)AR;
    float* C1O     = AR;
    f16*   AprojP  = (f16*)(ws + 8524288);            //  131,072 fl
    f16*   Cw1P    = (f16*)(ws + 8655360);            //  368,640 fl
    f16*   LlP     = (f16*)(ws + 9024000);            //  16,384 fl
    f16*   Xa      = (f16*)(ws + 9040384);            //  2,230,272 fl
    float* BRacc   = ws + 11270656;                   //  2,230,272 fl
    f16*   BRX     = (f16*)(ws + 13500928);           //  1,115,136 fl
    float* YB      = ws + 14616064;                   //  557,568 fl
    f16*   YBX     = (f16*)(ws + 15173632);           //  278,784 fl
    f16*   LL      = (f16*)(ws + 15452416);           //  798,768 fl
    f16*   CCX     = (f16*)(ws + 16251184);           //  5,325,120 fl
    f16*   Xll     = (f16*)(ws + 21576304);           //  4,260,096 fl
    float* XB      = ws + 25836400;                   //  565,794 fl
    float* POOLT32 = ws + 26402194;                   //  524,288 fl
    float* APROJT32= ws + 26926482;                   //  327,680 fl
    float* CW2T    = ws + 27254162;                   //  4,608 fl
    float* GP      = ws + 27258770;                   //  4,096 fl
    float* GPR     = ws + 27262866;                   //  512 fl
    float* GPC     = ws + 27263378;                   //  512 fl

    const long L0o = 0, L1o = 8421408, C0o = 17369154, C1oo = 17369410,
               F0o = 17369699, F1o = 25791107;

    hipMemsetAsync(GUARD, 0, 4096 * sizeof(float), stream);

    // head-independent packs
    tc_k<float, 0><<<dim3(35, 64, 2), TPB, 0, stream>>>(aspp_in, Xa, 2048, 1089, 2048, 0);
    tc_k<float, 0><<<dim3(521, 8, 2), TPB, 0, stream>>>(low_level, Xll, 256, 16641, 256, 0);
    gpool_k<<<4096, TPB, 0, stream>>>(aspp_in, GP, 1089, 1.0f / 1089.0f);

    for (int h = 0; h < 2; ++h) {
        const float* pw    = (const float*)d_in[2 + h * 10 + 0];
        const float* w0    = (const float*)d_in[2 + h * 10 + 1];
        const float* w1    = (const float*)d_in[2 + h * 10 + 2];
        const float* w2    = (const float*)d_in[2 + h * 10 + 3];
        const float* w3    = (const float*)d_in[2 + h * 10 + 4];
        const float* poolw = (const float*)d_in[2 + h * 10 + 5];
        const float* aproj = (const float*)d_in[2 + h * 10 + 6];
        const float* cw1   = (const float*)d_in[2 + h * 10 + 7];
        const float* cw2   = (const float*)d_in[2 + h * 10 + 8];
        const float* cb2   = (const float*)d_in[2 + h * 10 + 9];

        // pooled branch -> per-(b,c) bias prefilled into YB
        wtrans_f32<<<dim3(64, 8), TPB, 0, stream>>>(poolw, POOLT32, 256, 2048, 1);
        wtrans_f32<<<dim3(40, 8), TPB, 0, stream>>>(aproj, APROJT32, 256, 1280, 1);
        poolconv_k<<<2, TPB, 0, stream>>>(POOLT32, GP, GPR);
        gpc_k<<<2, TPB, 0, stream>>>(APROJT32, GPR, GPC);
        biasfill_k<<<2178, TPB, 0, stream>>>(GPC, YB);

        // weight packs
        packw_k<<<dim3(32, 16), TPB, 0, stream>>>(w0, Apack,           256, 2048, 2048, 1, 256, 32);
        packw_k<<<dim3(32, 16), TPB, 0, stream>>>(w1, Apack + 524288,  256, 2048, 2048, 9, 256, 32);
        packw_k<<<dim3(32, 16), TPB, 0, stream>>>(w2, Apack + 5242880, 256, 2048, 2048, 9, 256, 32);
        packw_k<<<dim3(32, 16), TPB, 0, stream>>>(w3, Apack + 9961472, 256, 2048, 2048, 9, 256, 32);
        packw_k<<<dim3(16, 16), TPB, 0, stream>>>(aproj, AprojP, 256, 1024, 1280, 1, 256, 16);
        packw_k<<<dim3(5, 16),  TPB, 0, stream>>>(cw1, Cw1P, 256, 304, 304, 9, 256, 5);
        packw_k<<<dim3(4, 8),   TPB, 0, stream>>>(pw, LlP, 48, 256, 256, 1, 128, 4);

        // fused ASPP (z = 28 branch-taps) -> atomic into zeroed BRacc
        hipMemsetAsync(BRacc, 0, 2230272 * sizeof(float), stream);
        mconv<2, 1, 0, 0><<<dim3(10, 2, 28), TPB, 0, stream>>>(
            Xa, Apack, GUARD, BRacc, 2048, 256, 33, 33, 1, 1,
            32, 0, 1024L * 1089, 2, 256);
        // relu + transpose -> BRX, then aproj (split-K z=4) atomic into YB
        tc_k<float, 1><<<dim3(35, 32, 2), TPB, 0, stream>>>(BRacc, BRX, 1024, 1089, 1024, 0);
        mconv<2, 0, 2, 0><<<dim3(10, 2, 4), TPB, 0, stream>>>(
            BRX, AprojP, GUARD, YB, 1024, 256, 33, 33, 1, 1,
            16, 4, 256L * 1089, 2, 256);
        // relu + transpose YB -> YBX
        tc_k<float, 1><<<dim3(35, 8, 2), TPB, 0, stream>>>(YB, YBX, 256, 1089, 256, 0);
        // low-level 1x1 (48ch, relu) -> LL f16 channel-major
        mconv<1, 0, 0, 1><<<dim3(66, 2, 1), TPB, 0, stream>>>(
            Xll, LlP, GUARD, LL, 256, 48, 129, 129, 1, 1,
            4, 0, 48L * 16641, 1, 128);
        // assemble CCX: memset (zero K-pad), LL -> cols 0..47, upsample -> cols 48..303
        hipMemsetAsync(CCX, 0, 10650240 * sizeof(f16), stream);
        tc_k<f16, 0><<<dim3(521, 2, 2), TPB, 0, stream>>>(LL, CCX, 48, 16641, 320, 0);
        ups2_k<<<4161, TPB, 0, stream>>>(YBX, CCX);
        // cw1 3x3 (z = 9 taps) -> atomic into zeroed C1O (relu deferred to cw2)
        hipMemsetAsync(C1O, 0, 8520192 * sizeof(float), stream);
        mconv<2, 0, 1, 0><<<dim3(132, 2, 9), TPB, 0, stream>>>(
            CCX, Cw1P, GUARD, C1O, 320, 256, 129, 129, 3, 1,
            5, 0, 256L * 16641, 2, 256);

        if (h == 0) {
            wtrans_f32<<<dim3(8, 1), TPB, 0, stream>>>(cw2, CW2T, 16, 256, 1);
            conv1x1_small<16><<<dim3(66, 2), TPB, 0, stream>>>(C1O, CW2T, cb2, XB, 16641);
            final_k<16><<<2057, TPB, 0, stream>>>(XB, o + L0o, o + F0o);
        } else {
            wtrans_f32<<<dim3(8, 1), TPB, 0, stream>>>(cw2, CW2T, 17, 256, 1);
            conv1x1_small<17><<<dim3(66, 2), TPB, 0, stream>>>(C1O, CW2T, cb2, XB, 16641);
            final_k<17><<<2057, TPB, 0, stream>>>(XB, o + L1o, o + F1o);
        }
    }
    centers_k<<<9, 64, 0, stream>>>(o + C0o, o + C1oo);
}

// Round 4
// 1225.425 us; speedup vs baseline: 8.3278x; 1.3850x over previous
//
#include <hip/hip_runtime.h>

#define TPB 256

typedef _Float16 f16;
typedef __attribute__((ext_vector_type(8))) _Float16 f16x8;
typedef __attribute__((ext_vector_type(16))) float f32x16;

#define GLD_LDS(g, l) __builtin_amdgcn_global_load_lds( \
    (const __attribute__((address_space(1))) void*)(g), \
    (__attribute__((address_space(3))) void*)(l), 16, 0, 0)

// ---------- weight pack: w[Cout][CinSrc][T] f32 -> Wp[t][kb][coP][64] f16 ----------
__global__ __launch_bounds__(TPB)
void packw_k(const float* __restrict__ w, f16* __restrict__ dst,
             int Cout, int CinUse, int CinSrc, int T, int coP, int KB)
{
    __shared__ float tile[16 * 577];
    const int RL = 64 * T;
    const int kb = blockIdx.x;
    const int coT = blockIdx.y;
    const int tid = threadIdx.x;
    const int n = 16 * RL;
    for (int idx = tid; idx < n; idx += TPB) {
        const int row = idx / RL;
        const int j = idx - row * RL;
        const int co = coT * 16 + row;
        const int k = kb * 64 + j / T;
        float v = 0.f;
        if (co < Cout && k < CinUse)
            v = w[((long)co * CinSrc + kb * 64) * T + j];
        tile[row * 577 + j] = v;
    }
    __syncthreads();
    const int nst = 128 * T;
    for (int idx = tid; idx < nst; idx += TPB) {
        const int g = idx & 7;
        const int t = (idx >> 3) % T;
        const int co = idx / (8 * T);
        f16x8 hv;
#pragma unroll
        for (int e = 0; e < 8; ++e)
            hv[e] = (f16)tile[co * 577 + (g * 8 + e) * T + t];
        *(f16x8*)&dst[(((long)t * KB + kb) * coP + coT * 16 + co) * 64 + g * 8] = hv;
    }
}

// ---------- transpose-cvt: src[B][C][HW] (f32 or f16) -> dst[B][HW][ldk] f16 at colOff ----------
template <typename ST, int RELU>
__global__ __launch_bounds__(TPB)
void tc_k(const ST* __restrict__ src, f16* __restrict__ dst,
          int C, int HW, int ldk, int colOff)
{
    __shared__ float t32[32 * 33];
    const int pT = blockIdx.x, cT = blockIdx.y, bb = blockIdx.z;
    const int tid = threadIdx.x;
#pragma unroll
    for (int pass = 0; pass < 4; ++pass) {
        const int ch = tid / 32 + pass * 8;
        const int px = tid % 32;
        const int c = cT * 32 + ch, p = pT * 32 + px;
        float v = 0.f;
        if (c < C && p < HW) v = (float)src[((long)bb * C + c) * HW + p];
        if (RELU) v = fmaxf(v, 0.f);
        t32[ch * 33 + px] = v;
    }
    __syncthreads();
#pragma unroll
    for (int pass = 0; pass < 4; ++pass) {
        const int px = tid / 32 + pass * 8;
        const int ch = tid % 32;
        const int p = pT * 32 + px, c = cT * 32 + ch;
        if (p < HW && c < C)
            dst[((long)bb * HW + p) * ldk + colOff + c] = (f16)t32[ch * 33 + px];
    }
}

// ---------- MFMA implicit-GEMM conv, global_load_lds staging, tap-accumulating ----------
// X: [B][NP][Cinp] f16 pixel-major. Wp: [t][uPerTap][coP][64] f16.
// Block 128(co) x 256(px), BK=64, 4 waves 2x2, wave tile 64x128.
// OUTMODE: 0=f32 store, 1=f16 store, 2=atomicAdd f32, 3=f16 pixel-major store (ldOut).
// ASPPZ: blockIdx.z = branch-tap, band-clipped tiles, K full per tap.
// else: flat work-units u=(tap,kb), z slices of zLen units, register accumulation.
template <int OUTMODE, int ASPPZ, int RELUOUT>
__global__ __launch_bounds__(TPB, 2)
void mconv(const f16* __restrict__ X, const f16* __restrict__ Wp,
           const f16* __restrict__ guard, void* __restrict__ out_,
           int Cinp, int Cout, int H, int W, int ks, int dil,
           int uPerTap, int zLen, int uTot, long outBStride, int nMtiles,
           int coP, int ldOut)
{
    __shared__ f16 Asm[128 * 64];
    __shared__ f16 Bsm[256 * 64];
    const int tid = threadIdx.x;
    const int b = blockIdx.y;
    const int mt = blockIdx.x % nMtiles, nt = blockIdx.x / nMtiles;
    const int co0 = mt * 128;
    const int NP = H * W;

    int tap0, kb0, uB, uE, dl = dil, kss = ks;
    long woff = 0, ooff = 0;
    int p0, pMax = NP;
    if (ASPPZ) {
        const int z = blockIdx.z;
        int br;
        if (z == 0) { br = 0; tap0 = 0; kss = 1; dl = 1; }
        else { br = 1 + (z - 1) / 9; tap0 = (z - 1) % 9; kss = 3;
               dl = (br == 1) ? 6 : (br == 2 ? 12 : 18); }
        woff = (br == 0) ? 0L : (br == 1 ? 524288L : (br == 2 ? 5242880L : 9961472L));
        ooff = (long)br * 278784L;
        const int dy0 = (tap0 / kss - (kss >> 1)) * dl;
        const int yLo = max(0, -dy0), yHi = min(H, H - dy0);
        p0 = yLo * W + nt * 256;
        pMax = yHi * W;
        if (p0 >= pMax) return;
        uB = 0; uE = uPerTap; kb0 = 0;
    } else {
        p0 = nt * 256;
        uB = blockIdx.z * zLen; uE = min(uTot, uB + zLen);
        tap0 = uB / uPerTap; kb0 = uB - tap0 * uPerTap;
    }
    const int half = kss >> 1;

    // per-row pixel coords (tap-independent)
    const int qq = tid & 7;
    int pyA[8], pxA[8];
    unsigned pvMask = 0;
#pragma unroll
    for (int r = 0; r < 8; ++r) {
        const int row = r * 32 + (tid >> 3);
        const int p = p0 + row;
        const bool v = p < pMax;
        const int py = v ? p / W : 0;
        pyA[r] = py; pxA[r] = v ? p - py * W : 0;
        if (v) pvMask |= 1u << r;
    }
    // A source offsets (4 rounds x 32 rows)
    int aoff[4];
#pragma unroll
    for (int r = 0; r < 4; ++r) {
        const int co = r * 32 + (tid >> 3);
        aoff[r] = co * 64 + ((qq ^ (co & 7)) << 3);
    }

    const int lane = tid & 63, wid = tid >> 6;
    const int wm = wid >> 1, wn = wid & 1;
    const int r32 = lane & 31, hh = lane >> 5;
    const int rA0 = wm * 64 + r32;
    const int key = r32 & 7;

    f32x16 acc[2][4];
#pragma unroll
    for (int i = 0; i < 2; ++i)
#pragma unroll
        for (int j = 0; j < 4; ++j) acc[i][j] = (f32x16)(0.f);

    char* AsmB = (char*)Asm;
    char* BsmB = (char*)Bsm;
    const int wofs = wid * 1024;

    const f16* srcB[8];
    const f16* Wtap = Wp;
    int tap = tap0, kb = kb0;
    bool fresh = true;

    for (int u = uB; u < uE; ++u) {
        if (fresh) {
            fresh = false;
            const int ky = tap / kss, kx = tap - ky * kss;
            const int dy = (ky - half) * dl, dx = (kx - half) * dl;
#pragma unroll
            for (int r = 0; r < 8; ++r) {
                const int row = r * 32 + (tid >> 3);
                const int sy = pyA[r] + dy, sx = pxA[r] + dx;
                const bool v = ((pvMask >> r) & 1) &&
                               ((unsigned)sy < (unsigned)H) && ((unsigned)sx < (unsigned)W);
                const int swz = (qq ^ (row & 7)) << 3;
                srcB[r] = v ? (X + ((long)b * NP + (long)sy * W + sx) * Cinp + swz)
                            : (guard + swz);
            }
            Wtap = Wp + woff + ((long)tap * uPerTap * coP + (long)co0) * 64;
        }
        __syncthreads();
        const f16* wsrc = Wtap + (long)kb * coP * 64;
#pragma unroll
        for (int r = 0; r < 4; ++r)
            GLD_LDS(wsrc + aoff[r], AsmB + r * 4096 + wofs);
#pragma unroll
        for (int r = 0; r < 8; ++r)
            GLD_LDS(srcB[r] + (long)kb * 64, BsmB + r * 4096 + wofs);
        __syncthreads();
#pragma unroll
        for (int kh = 0; kh < 4; ++kh) {
            const int g = (((kh * 2 + hh) ^ key) << 4);
            const f16x8 a0 = *(const f16x8*)(AsmB + rA0 * 128 + g);
            const f16x8 a1 = *(const f16x8*)(AsmB + (rA0 + 32) * 128 + g);
            const int bBase = (wn * 128 + r32) * 128 + g;
            const f16x8 b0 = *(const f16x8*)(BsmB + bBase);
            const f16x8 b1 = *(const f16x8*)(BsmB + bBase + 32 * 128);
            const f16x8 b2 = *(const f16x8*)(BsmB + bBase + 64 * 128);
            const f16x8 b3 = *(const f16x8*)(BsmB + bBase + 96 * 128);
            acc[0][0] = __builtin_amdgcn_mfma_f32_32x32x16_f16(a0, b0, acc[0][0], 0, 0, 0);
            acc[0][1] = __builtin_amdgcn_mfma_f32_32x32x16_f16(a0, b1, acc[0][1], 0, 0, 0);
            acc[0][2] = __builtin_amdgcn_mfma_f32_32x32x16_f16(a0, b2, acc[0][2], 0, 0, 0);
            acc[0][3] = __builtin_amdgcn_mfma_f32_32x32x16_f16(a0, b3, acc[0][3], 0, 0, 0);
            acc[1][0] = __builtin_amdgcn_mfma_f32_32x32x16_f16(a1, b0, acc[1][0], 0, 0, 0);
            acc[1][1] = __builtin_amdgcn_mfma_f32_32x32x16_f16(a1, b1, acc[1][1], 0, 0, 0);
            acc[1][2] = __builtin_amdgcn_mfma_f32_32x32x16_f16(a1, b2, acc[1][2], 0, 0, 0);
            acc[1][3] = __builtin_amdgcn_mfma_f32_32x32x16_f16(a1, b3, acc[1][3], 0, 0, 0);
        }
        if (++kb == uPerTap) { kb = 0; ++tap; fresh = true; }
    }

    const long outB = (long)b * outBStride + ooff;
#pragma unroll
    for (int mi = 0; mi < 2; ++mi)
#pragma unroll
    for (int ni = 0; ni < 4; ++ni)
#pragma unroll
    for (int j = 0; j < 16; ++j) {
        const int m = wm * 64 + mi * 32 + 4 * hh + (j & 3) + 8 * (j >> 2);
        const int n = wn * 128 + ni * 32 + r32;
        const int co = co0 + m;
        const int p = p0 + n;
        if (co < Cout && p < pMax) {
            float v = acc[mi][ni][j];
            if (RELUOUT) v = fmaxf(v, 0.f);
            if (OUTMODE == 0)      ((float*)out_)[outB + (long)co * NP + p] = v;
            else if (OUTMODE == 1) ((f16*)out_)[outB + (long)co * NP + p] = (f16)v;
            else if (OUTMODE == 3) ((f16*)out_)[outB + (long)p * ldOut + co] = (f16)v;
            else atomicAdd(&((float*)out_)[outB + (long)co * NP + p], v);
        }
    }
}

// ---------- small helpers ----------
__global__ __launch_bounds__(TPB)
void wtrans_f32(const float* __restrict__ w, float* __restrict__ wT,
                int Cout, int Cin, int T)
{
    __shared__ float tile[32 * (32 * 9 + 1)];
    const int rowlen = 32 * T + 1;
    const int co0 = blockIdx.y * 32;
    const int ci0 = blockIdx.x * 32;
    const int n = 32 * 32 * T;
    const int tid = threadIdx.x;
    for (int l = tid; l < n; l += TPB) {
        int co = l / (32 * T);
        int rem = l - co * (32 * T);
        int ci = rem / T;
        float v = 0.f;
        if (co0 + co < Cout && ci0 + ci < Cin)
            v = w[(size_t)(co0 + co) * Cin * T + (size_t)ci0 * T + rem];
        tile[co * rowlen + rem] = v;
    }
    __syncthreads();
    for (int l = tid; l < n; l += TPB) {
        int co = l & 31;
        int ci = (l >> 5) & 31;
        int t = l >> 10;
        if (co0 + co < Cout && ci0 + ci < Cin)
            wT[((size_t)t * Cin + (ci0 + ci)) * Cout + (co0 + co)] = tile[co * rowlen + ci * T + t];
    }
}

__global__ __launch_bounds__(TPB)
void gpool_k(const float* __restrict__ in, float* __restrict__ gp, int HW, float inv)
{
    const int bc = blockIdx.x;
    const float* p = in + (size_t)bc * HW;
    float s = 0.f;
    for (int i = threadIdx.x; i < HW; i += TPB) s += p[i];
#pragma unroll
    for (int off = 32; off > 0; off >>= 1) s += __shfl_down(s, off, 64);
    __shared__ float red[4];
    if ((threadIdx.x & 63) == 0) red[threadIdx.x >> 6] = s;
    __syncthreads();
    if (threadIdx.x == 0) gp[bc] = (red[0] + red[1] + red[2] + red[3]) * inv;
}

__global__ __launch_bounds__(TPB)
void poolconv_k(const float* __restrict__ poolT, const float* __restrict__ gp,
                float* __restrict__ gpr)
{
    const int b = blockIdx.x, c = threadIdx.x;
    const float* g = gp + (size_t)b * 2048;
    float s = 0.f;
    for (int k = 0; k < 2048; ++k) s = fmaf(poolT[(size_t)k * 256 + c], g[k], s);
    gpr[b * 256 + c] = fmaxf(s, 0.f);
}

__global__ __launch_bounds__(TPB)
void gpc_k(const float* __restrict__ aprojT, const float* __restrict__ gpr,
           float* __restrict__ gpc)
{
    const int b = blockIdx.x, c = threadIdx.x;
    const float* g = gpr + (size_t)b * 256;
    const float* w = aprojT + (size_t)1024 * 256;
    float s = 0.f;
    for (int j = 0; j < 256; ++j) s = fmaf(w[(size_t)j * 256 + c], g[j], s);
    gpc[b * 256 + c] = s;
}

__global__ __launch_bounds__(TPB)
void biasfill_k(const float* __restrict__ gpc, float* __restrict__ yb)
{
    const int idx = blockIdx.x * TPB + threadIdx.x;
    if (idx >= 2 * 256 * 1089) return;
    const int c = (idx / 1089) & 255;
    const int b = idx / (256 * 1089);
    yb[idx] = gpc[b * 256 + c];
}

// ---------- upsample 33->129 from pixel-major YBX, writes CCX cols 48..303 ----------
__global__ __launch_bounds__(TPB)
void ups2_k(const f16* __restrict__ ybx, f16* __restrict__ ccx)
{
    const int idx = blockIdx.x * TPB + threadIdx.x;
    if (idx >= 2 * 16641 * 32) return;
    const int cg = idx & 31;
    const int p = (idx >> 5) % 16641;
    const int b = idx / (16641 * 32);
    const int oy = p / 129, ox = p % 129;
    const float sc = 33.0f / 129.0f;
    const float sx = (ox + 0.5f) * sc - 0.5f;
    const float sy = (oy + 0.5f) * sc - 0.5f;
    int ix0 = (int)floorf(sx), iy0 = (int)floorf(sy);
    const float fx = sx - ix0, fy = sy - iy0;
    int ix1 = min(32, max(0, ix0 + 1)); ix0 = min(32, max(0, ix0));
    int iy1 = min(32, max(0, iy0 + 1)); iy0 = min(32, max(0, iy0));
    const f16* base = ybx + (long)b * 1089 * 256 + cg * 8;
    const f16x8 v00 = *(const f16x8*)(base + ((long)iy0 * 33 + ix0) * 256);
    const f16x8 v01 = *(const f16x8*)(base + ((long)iy0 * 33 + ix1) * 256);
    const f16x8 v10 = *(const f16x8*)(base + ((long)iy1 * 33 + ix0) * 256);
    const f16x8 v11 = *(const f16x8*)(base + ((long)iy1 * 33 + ix1) * 256);
    f16x8 r;
#pragma unroll
    for (int e = 0; e < 8; ++e) {
        const float a0 = (float)v00[e] + ((float)v01[e] - (float)v00[e]) * fx;
        const float a1 = (float)v10[e] + ((float)v11[e] - (float)v10[e]) * fx;
        r[e] = (f16)(a0 + (a1 - a0) * fy);
    }
    *(f16x8*)(ccx + ((long)b * 16641 + p) * 320 + 48 + cg * 8) = r;
}

// ---------- cw2 1x1 conv (relu on input) ----------
template <int NC>
__global__ __launch_bounds__(TPB)
void conv1x1_small(const float* __restrict__ in, const float* __restrict__ wT,
                   const float* __restrict__ bias, float* __restrict__ out, int HW)
{
    __shared__ float wsm[256 * NC];
    const int tid = threadIdx.x;
    for (int l = tid; l < 256 * NC; l += TPB) wsm[l] = wT[l];
    __syncthreads();
    const int b = blockIdx.y;
    const int p = blockIdx.x * TPB + tid;
    if (p >= HW) return;
    const float* inB = in + (size_t)b * 256 * HW + p;
    float acc[NC];
#pragma unroll
    for (int c = 0; c < NC; ++c) acc[c] = 0.f;
    for (int k = 0; k < 256; ++k) {
        const float x = fmaxf(inB[(size_t)k * HW], 0.f);
#pragma unroll
        for (int c = 0; c < NC; ++c) acc[c] = fmaf(wsm[k * NC + c], x, acc[c]);
    }
    float* oB = out + (size_t)b * NC * HW + p;
#pragma unroll
    for (int c = 0; c < NC; ++c) oB[(size_t)c * HW] = acc[c] + bias[c];
}

// ---------- final: 129->513 bilinear + logits + NHWC features ----------
template <int NC>
__global__ __launch_bounds__(TPB)
void final_k(const float* __restrict__ x, float* __restrict__ logits,
             float* __restrict__ feats)
{
    const int idx = blockIdx.x * TPB + threadIdx.x;
    const long HW = 513L * 513L;
    if (idx >= 2 * 513 * 513) return;
    const int ox = idx % 513;
    int r = idx / 513;
    const int oy = r % 513;
    const int b = r / 513;
    const float sc = 129.0f / 513.0f;
    const float sx = (ox + 0.5f) * sc - 0.5f;
    const float sy = (oy + 0.5f) * sc - 0.5f;
    int ix0 = (int)floorf(sx), iy0 = (int)floorf(sy);
    const float fx = sx - ix0, fy = sy - iy0;
    int ix1 = min(128, max(0, ix0 + 1)); ix0 = min(128, max(0, ix0));
    int iy1 = min(128, max(0, iy0 + 1)); iy0 = min(128, max(0, iy0));
    const float* xb = x + (size_t)b * NC * 16641;
    const int i00 = iy0 * 129 + ix0, i01 = iy0 * 129 + ix1;
    const int i10 = iy1 * 129 + ix0, i11 = iy1 * 129 + ix1;
    float v[NC];
    float ss = 0.f;
#pragma unroll
    for (int c = 0; c < NC; ++c) {
        const float* s = xb + (size_t)c * 16641;
        const float a0 = s[i00] + (s[i01] - s[i00]) * fx;
        const float a1 = s[i10] + (s[i11] - s[i10]) * fx;
        const float vv = a0 + (a1 - a0) * fy;
        v[c] = vv;
        ss = fmaf(vv, vv, ss);
    }
    const long pix = (long)oy * 513 + ox;
#pragma unroll
    for (int c = 0; c < NC; ++c)
        logits[((size_t)b * NC + c) * HW + pix] = fmaf(6.f, v[c], -ss - 9.f);
    float* f = feats + ((size_t)b * HW + pix) * NC;
#pragma unroll
    for (int c = 0; c < NC; ++c) f[c] = v[c];
}

__global__ void centers_k(float* __restrict__ c0, float* __restrict__ c1)
{
    const int t = blockIdx.x * 64 + threadIdx.x;
    if (t < 256) c0[t] = (t / 16 == t % 16) ? 3.f : 0.f;
    const int u = t - 256;
    if (u >= 0 && u < 289) c1[u] = (u / 17 == u % 17) ? 3.f : 0.f;
}

// ---------------- host ----------------
extern "C" void kernel_launch(void* const* d_in, const int* in_sizes, int n_in,
                              void* d_out, int out_size, void* d_ws, size_t ws_size,
                              hipStream_t stream)
{
    const float* low_level = (const float*)d_in[0];
    const float* aspp_in   = (const float*)d_in[1];
    float* ws = (float*)d_ws;
    float* o  = (float*)d_out;

    // ---- ws layout (floats) ----
    f16*   GUARD   = (f16*)(ws + 0);                  //  4,096 fl (zeros)
    float* AR      = ws + 4096;                       //  8,520,192 fl: Apack, later C1O (alias)
    f16*   Apack   = (f16*)AR;
    float* C1O     = AR;
    f16*   AprojP  = (f16*)(ws + 8524288);            //  131,072 fl
    f16*   Cw1P    = (f16*)(ws + 8655360);            //  368,640 fl
    f16*   LlP     = (f16*)(ws + 9024000);            //  16,384 fl
    f16*   Xa      = (f16*)(ws + 9040384);            //  2,230,272 fl
    float* BRacc   = ws + 11270656;                   //  2,230,272 fl
    f16*   BRX     = (f16*)(ws + 13500928);           //  1,115,136 fl
    float* YB      = ws + 14616064;                   //    557,568 fl
    f16*   YBX     = (f16*)(ws + 15173632);           //    278,784 fl
    f16*   CCX     = (f16*)(ws + 16251184);           //  5,325,120 fl
    f16*   Xll     = (f16*)(ws + 21576304);           //  4,260,096 fl
    float* XB      = ws + 25836400;                   //    565,794 fl
    float* POOLT32 = ws + 26402194;                   //    524,288 fl
    float* APROJT32= ws + 26926482;                   //    327,680 fl
    float* CW2T    = ws + 27254162;                   //      4,608 fl
    float* GP      = ws + 27258770;                   //      4,096 fl
    float* GPR     = ws + 27262866;                   //        512 fl
    float* GPC     = ws + 27263378;                   //        512 fl

    const long L0o = 0, L1o = 8421408, C0o = 17369154, C1oo = 17369410,
               F0o = 17369699, F1o = 25791107;

    hipMemsetAsync(GUARD, 0, 4096 * sizeof(float), stream);
    hipMemsetAsync(CCX, 0, 10650240 * sizeof(f16), stream);  // once: pad cols stay 0

    // head-independent packs
    tc_k<float, 0><<<dim3(35, 64, 2), TPB, 0, stream>>>(aspp_in, Xa, 2048, 1089, 2048, 0);
    tc_k<float, 0><<<dim3(521, 8, 2), TPB, 0, stream>>>(low_level, Xll, 256, 16641, 256, 0);
    gpool_k<<<4096, TPB, 0, stream>>>(aspp_in, GP, 1089, 1.0f / 1089.0f);

    for (int h = 0; h < 2; ++h) {
        const float* pw    = (const float*)d_in[2 + h * 10 + 0];
        const float* w0    = (const float*)d_in[2 + h * 10 + 1];
        const float* w1    = (const float*)d_in[2 + h * 10 + 2];
        const float* w2    = (const float*)d_in[2 + h * 10 + 3];
        const float* w3    = (const float*)d_in[2 + h * 10 + 4];
        const float* poolw = (const float*)d_in[2 + h * 10 + 5];
        const float* aproj = (const float*)d_in[2 + h * 10 + 6];
        const float* cw1   = (const float*)d_in[2 + h * 10 + 7];
        const float* cw2   = (const float*)d_in[2 + h * 10 + 8];
        const float* cb2   = (const float*)d_in[2 + h * 10 + 9];

        // pooled branch -> per-(b,c) bias prefilled into YB
        wtrans_f32<<<dim3(64, 8), TPB, 0, stream>>>(poolw, POOLT32, 256, 2048, 1);
        wtrans_f32<<<dim3(40, 8), TPB, 0, stream>>>(aproj, APROJT32, 256, 1280, 1);
        poolconv_k<<<2, TPB, 0, stream>>>(POOLT32, GP, GPR);
        gpc_k<<<2, TPB, 0, stream>>>(APROJT32, GPR, GPC);
        biasfill_k<<<2178, TPB, 0, stream>>>(GPC, YB);

        // weight packs
        packw_k<<<dim3(32, 16), TPB, 0, stream>>>(w0, Apack,           256, 2048, 2048, 1, 256, 32);
        packw_k<<<dim3(32, 16), TPB, 0, stream>>>(w1, Apack + 524288,  256, 2048, 2048, 9, 256, 32);
        packw_k<<<dim3(32, 16), TPB, 0, stream>>>(w2, Apack + 5242880, 256, 2048, 2048, 9, 256, 32);
        packw_k<<<dim3(32, 16), TPB, 0, stream>>>(w3, Apack + 9961472, 256, 2048, 2048, 9, 256, 32);
        packw_k<<<dim3(16, 16), TPB, 0, stream>>>(aproj, AprojP, 256, 1024, 1280, 1, 256, 16);
        packw_k<<<dim3(5, 16),  TPB, 0, stream>>>(cw1, Cw1P, 256, 304, 304, 9, 256, 5);
        packw_k<<<dim3(4, 8),   TPB, 0, stream>>>(pw, LlP, 48, 256, 256, 1, 128, 4);

        // fused ASPP (z = 28 branch-taps, band-clipped) -> atomic into zeroed BRacc
        hipMemsetAsync(BRacc, 0, 2230272 * sizeof(float), stream);
        mconv<2, 1, 0><<<dim3(10, 2, 28), TPB, 0, stream>>>(
            Xa, Apack, GUARD, BRacc, 2048, 256, 33, 33, 3, 1,
            32, 0, 32, 1024L * 1089, 2, 256, 0);
        // relu + transpose -> BRX, then aproj (split-K z=4) atomic into YB
        tc_k<float, 1><<<dim3(35, 32, 2), TPB, 0, stream>>>(BRacc, BRX, 1024, 1089, 1024, 0);
        mconv<2, 0, 0><<<dim3(10, 2, 4), TPB, 0, stream>>>(
            BRX, AprojP, GUARD, YB, 1024, 256, 33, 33, 1, 1,
            16, 4, 16, 256L * 1089, 2, 256, 0);
        // relu + transpose YB -> YBX
        tc_k<float, 1><<<dim3(35, 8, 2), TPB, 0, stream>>>(YB, YBX, 256, 1089, 256, 0);
        // low-level 1x1 (48ch, relu) -> CCX cols 0..47 (pixel-major f16 store)
        mconv<3, 0, 1><<<dim3(66, 2, 1), TPB, 0, stream>>>(
            Xll, LlP, GUARD, CCX, 256, 48, 129, 129, 1, 1,
            4, 4, 4, 16641L * 320, 1, 128, 320);
        // upsample 33->129 -> CCX cols 48..303
        ups2_k<<<4161, TPB, 0, stream>>>(YBX, CCX);
        // cw1 3x3 (tap-accumulating, split-U z=2) -> atomic into zeroed C1O
        hipMemsetAsync(C1O, 0, 8520192 * sizeof(float), stream);
        mconv<2, 0, 0><<<dim3(132, 2, 2), TPB, 0, stream>>>(
            CCX, Cw1P, GUARD, C1O, 320, 256, 129, 129, 3, 1,
            5, 23, 45, 256L * 16641, 2, 256, 0);

        if (h == 0) {
            wtrans_f32<<<dim3(8, 1), TPB, 0, stream>>>(cw2, CW2T, 16, 256, 1);
            conv1x1_small<16><<<dim3(66, 2), TPB, 0, stream>>>(C1O, CW2T, cb2, XB, 16641);
            final_k<16><<<2057, TPB, 0, stream>>>(XB, o + L0o, o + F0o);
        } else {
            wtrans_f32<<<dim3(8, 1), TPB, 0, stream>>>(cw2, CW2T, 17, 256, 1);
            conv1x1_small<17><<<dim3(66, 2), TPB, 0, stream>>>(C1O, CW2T, cb2, XB, 16641);
            final_k<17><<<2057, TPB, 0, stream>>>(XB, o + L1o, o + F1o);
        }
    }
    centers_k<<<9, 64, 0, stream>>>(o + C0o, o + C1oo);
}